// Round 1
// baseline (490.679 us; speedup 1.0000x reference)
//
#include <hip/hip_runtime.h>
#include <cstdint>
#include <math.h>

typedef float f32x4 __attribute__((ext_vector_type(4)));
typedef __bf16 bf16x8 __attribute__((ext_vector_type(8)));
typedef unsigned short u16x8 __attribute__((ext_vector_type(8)));
typedef unsigned short u16x4 __attribute__((ext_vector_type(4)));

typedef __attribute__((address_space(1))) const void* gas_cvptr;
typedef __attribute__((address_space(3))) void* las_vptr;

__device__ __forceinline__ unsigned short f32_to_bf16(float f) {
  uint32_t u = __builtin_bit_cast(uint32_t, f);
  u += 0x7FFFu + ((u >> 16) & 1u);   // round-to-nearest-even
  return (unsigned short)(u >> 16);
}

__device__ __forceinline__ bf16x8 ld_bf16x8(const unsigned short* p) {
  return __builtin_bit_cast(bf16x8, *(const u16x8*)p);
}

// ---------------- convert x: f32 -> bf16 ----------------
__global__ void cvt_x(const float* __restrict__ x, unsigned short* __restrict__ xb, int n4) {
  int stride = gridDim.x * blockDim.x;
  for (int i = blockIdx.x * blockDim.x + threadIdx.x; i < n4; i += stride) {
    float4 v = ((const float4*)x)[i];
    u16x4 o = { f32_to_bf16(v.x), f32_to_bf16(v.y), f32_to_bf16(v.z), f32_to_bf16(v.w) };
    ((u16x4*)xb)[i] = o;
  }
}

// ------------- transpose weights [K][N] f32 -> [N][K] bf16 -------------
// z: 0=wq,1=wk,2=wv -> wqkvT + z*1024*1024 ; 3=wo -> woT
__global__ void cvt_w(const float* __restrict__ wq, const float* __restrict__ wk,
                      const float* __restrict__ wv, const float* __restrict__ wo,
                      unsigned short* __restrict__ wqkvT, unsigned short* __restrict__ woT) {
  const int z = blockIdx.z;
  const float* __restrict__ w = (z == 0) ? wq : (z == 1) ? wk : (z == 2) ? wv : wo;
  unsigned short* __restrict__ out = (z < 3) ? (wqkvT + (size_t)z * 1024 * 1024) : woT;
  __shared__ float tile[64][65];
  const int r0 = blockIdx.y * 64;  // k dim
  const int c0 = blockIdx.x * 64;  // n dim
  const int t = threadIdx.x;
#pragma unroll
  for (int i = 0; i < 4; i++) {
    int row = (t >> 4) + i * 16;
    int col = (t & 15) * 4;
    float4 v = *(const float4*)&w[(size_t)(r0 + row) * 1024 + c0 + col];
    tile[row][col] = v.x; tile[row][col + 1] = v.y;
    tile[row][col + 2] = v.z; tile[row][col + 3] = v.w;
  }
  __syncthreads();
#pragma unroll
  for (int i = 0; i < 2; i++) {
    int nr = (t >> 3) + i * 32;
    int kc = (t & 7) * 8;
    u16x8 o;
#pragma unroll
    for (int j = 0; j < 8; j++) o[j] = f32_to_bf16(tile[kc + j][nr]);
    *(u16x8*)&out[(size_t)(c0 + nr) * 1024 + r0 + kc] = o;
  }
}

// ---------------- GEMM: C[M][N] = A[M][K] @ Bt[N][K]^T (+bias, epi) ----------------
// EPI=0: scatter bf16 into Q/K/V [B][H][S][DH] with per-part bias
// EPI=1: f32 out = gelu_exact(acc + bias)
template <int EPI>
__global__ __launch_bounds__(256) void gemm_bt(
    const unsigned short* __restrict__ A, const unsigned short* __restrict__ Bt,
    const float* __restrict__ b0, const float* __restrict__ b1, const float* __restrict__ b2,
    unsigned short* __restrict__ Qb, unsigned short* __restrict__ Kb, unsigned short* __restrict__ Vb,
    float* __restrict__ Out, int Ncols, int Ktot) {
  __shared__ __align__(16) unsigned short As[128 * 32];
  __shared__ __align__(16) unsigned short Bs[128 * 32];
  const int nb = Ncols >> 7;
  const int tm = blockIdx.x / nb, tn = blockIdx.x % nb;
  const int rowBase = tm << 7, colBase = tn << 7;
  const int t = threadIdx.x;
  const int lane = t & 63, w = t >> 6;
  const int li = lane & 15, lg = lane >> 4;
  const int wr = (w >> 1) * 64, wc = (w & 1) * 64;

  f32x4 acc[4][4] = {};

  for (int kt = 0; kt < Ktot; kt += 32) {
    __syncthreads();
#pragma unroll
    for (int half = 0; half < 2; half++) {
      const int c = t + half * 256;            // chunk 0..511, 16B each
      const unsigned short* gA = A + (size_t)(rowBase + (c >> 2)) * Ktot + kt + (c & 3) * 8;
      __builtin_amdgcn_global_load_lds((gas_cvptr)gA,
          (las_vptr)(As + (size_t)(w * 64 + half * 256) * 8), 16, 0, 0);
      const unsigned short* gB = Bt + (size_t)(colBase + (c >> 2)) * Ktot + kt + (c & 3) * 8;
      __builtin_amdgcn_global_load_lds((gas_cvptr)gB,
          (las_vptr)(Bs + (size_t)(w * 64 + half * 256) * 8), 16, 0, 0);
    }
    __syncthreads();
    bf16x8 af[4], bfr[4];
#pragma unroll
    for (int m = 0; m < 4; m++) af[m] = ld_bf16x8(As + (wr + m * 16 + li) * 32 + lg * 8);
#pragma unroll
    for (int n = 0; n < 4; n++) bfr[n] = ld_bf16x8(Bs + (wc + n * 16 + li) * 32 + lg * 8);
#pragma unroll
    for (int m = 0; m < 4; m++)
#pragma unroll
      for (int n = 0; n < 4; n++)
        acc[m][n] = __builtin_amdgcn_mfma_f32_16x16x32_bf16(af[m], bfr[n], acc[m][n], 0, 0, 0);
  }

  if (EPI == 0) {
    const int part = colBase >> 10;  // 0=Q 1=K 2=V (128 | 1024 so uniform per block)
    const float* __restrict__ bias = (part == 0) ? b0 : (part == 1) ? b1 : b2;
    unsigned short* __restrict__ dst = (part == 0) ? Qb : (part == 1) ? Kb : Vb;
#pragma unroll
    for (int m = 0; m < 4; m++) {
      const int rowb = rowBase + wr + m * 16 + lg * 4;
#pragma unroll
      for (int r = 0; r < 4; r++) {
        const int row = rowb + r;
        const int b = row >> 6, s = row & 63;
#pragma unroll
        for (int n = 0; n < 4; n++) {
          const int col = colBase + wc + n * 16 + li;
          const int within = col & 1023;
          const int h = within >> 6, dh = within & 63;
          float v = acc[m][n][r] + bias[within];
          dst[(size_t)((b * 16 + h) * 64 + s) * 64 + dh] = f32_to_bf16(v);
        }
      }
    }
  } else {
#pragma unroll
    for (int m = 0; m < 4; m++) {
      const int rowb = rowBase + wr + m * 16 + lg * 4;
#pragma unroll
      for (int r = 0; r < 4; r++) {
#pragma unroll
        for (int n = 0; n < 4; n++) {
          const int col = colBase + wc + n * 16 + li;
          float v = acc[m][n][r] + b0[col];
          v = 0.5f * v * (1.0f + erff(v * 0.70710678118654752f));
          Out[(size_t)(rowb + r) * 1024 + col] = v;
        }
      }
    }
  }
}

// ---------------- attention per (b,h): 64x64, softmax, PV ----------------
__global__ __launch_bounds__(256) void attn(
    const unsigned short* __restrict__ Qb, const unsigned short* __restrict__ Kb,
    const unsigned short* __restrict__ Vb, unsigned short* __restrict__ ctx) {
  __shared__ __align__(16) unsigned short Qs[64][72];
  __shared__ __align__(16) unsigned short Ks[64][72];
  __shared__ __align__(16) unsigned short Vt[64][72];   // transposed: [dh][s]
  __shared__ __align__(16) unsigned short Ps[64][72];
  const int bh = blockIdx.x;
  const int b = bh >> 4, h = bh & 15;
  const int t = threadIdx.x, lane = t & 63, w = t >> 6;
  const int li = lane & 15, lg = lane >> 4;
  const unsigned short* __restrict__ Qg = Qb + (size_t)bh * 4096;
  const unsigned short* __restrict__ Kg = Kb + (size_t)bh * 4096;
  const unsigned short* __restrict__ Vg = Vb + (size_t)bh * 4096;

#pragma unroll
  for (int i = 0; i < 2; i++) {
    const int c = t + i * 256;
    const int row = c >> 3, col8 = (c & 7) * 8;
    *(u16x8*)&Qs[row][col8] = *(const u16x8*)&Qg[row * 64 + col8];
    *(u16x8*)&Ks[row][col8] = *(const u16x8*)&Kg[row * 64 + col8];
    u16x8 v = *(const u16x8*)&Vg[row * 64 + col8];
#pragma unroll
    for (int j = 0; j < 8; j++) Vt[col8 + j][row] = v[j];
  }
  __syncthreads();

  // scores: wave w owns q-rows 16w..16w+15
  f32x4 sc[4] = {};
#pragma unroll
  for (int ks = 0; ks < 2; ks++) {
    bf16x8 qa = ld_bf16x8(&Qs[w * 16 + li][ks * 32 + lg * 8]);
#pragma unroll
    for (int n = 0; n < 4; n++) {
      bf16x8 kf = ld_bf16x8(&Ks[n * 16 + li][ks * 32 + lg * 8]);
      sc[n] = __builtin_amdgcn_mfma_f32_16x16x32_bf16(qa, kf, sc[n], 0, 0, 0);
    }
  }

  // wave-parallel softmax over 64 cols; row q = 16w + lg*4 + r lives on the 16
  // lanes sharing lg; reduce with xor-shuffles 1,2,4,8.
#pragma unroll
  for (int r = 0; r < 4; r++) {
    float v0 = sc[0][r] * 0.03125f, v1 = sc[1][r] * 0.03125f;
    float v2 = sc[2][r] * 0.03125f, v3 = sc[3][r] * 0.03125f;
    float mx = fmaxf(fmaxf(v0, v1), fmaxf(v2, v3));
#pragma unroll
    for (int off = 1; off < 16; off <<= 1) mx = fmaxf(mx, __shfl_xor(mx, off, 64));
    float e0 = __expf(v0 - mx), e1 = __expf(v1 - mx);
    float e2 = __expf(v2 - mx), e3 = __expf(v3 - mx);
    float sum = e0 + e1 + e2 + e3;
#pragma unroll
    for (int off = 1; off < 16; off <<= 1) sum += __shfl_xor(sum, off, 64);
    float is = 1.0f / sum;
    const int q = w * 16 + lg * 4 + r;
    Ps[q][0 * 16 + li] = f32_to_bf16(e0 * is);
    Ps[q][1 * 16 + li] = f32_to_bf16(e1 * is);
    Ps[q][2 * 16 + li] = f32_to_bf16(e2 * is);
    Ps[q][3 * 16 + li] = f32_to_bf16(e3 * is);
  }
  __syncthreads();

  // PV: D[q][dh] = sum_k P[q][k] * V[k][dh], V from transposed tile
  f32x4 oc[4] = {};
#pragma unroll
  for (int ks = 0; ks < 2; ks++) {
    bf16x8 pa = ld_bf16x8(&Ps[w * 16 + li][ks * 32 + lg * 8]);
#pragma unroll
    for (int n = 0; n < 4; n++) {
      bf16x8 vf = ld_bf16x8(&Vt[n * 16 + li][ks * 32 + lg * 8]);
      oc[n] = __builtin_amdgcn_mfma_f32_16x16x32_bf16(pa, vf, oc[n], 0, 0, 0);
    }
  }
#pragma unroll
  for (int n = 0; n < 4; n++)
#pragma unroll
    for (int r = 0; r < 4; r++)
      ctx[(size_t)(b * 64 + w * 16 + lg * 4 + r) * 1024 + h * 64 + n * 16 + li] =
          f32_to_bf16(oc[n][r]);
}

extern "C" void kernel_launch(void* const* d_in, const int* in_sizes, int n_in,
                              void* d_out, int out_size, void* d_ws, size_t ws_size,
                              hipStream_t stream) {
  const float* x  = (const float*)d_in[0];
  const float* wq = (const float*)d_in[1];
  const float* bq = (const float*)d_in[2];
  const float* wk = (const float*)d_in[3];
  const float* bk = (const float*)d_in[4];
  const float* wv = (const float*)d_in[5];
  const float* bv = (const float*)d_in[6];
  const float* wo = (const float*)d_in[7];
  const float* bo = (const float*)d_in[8];
  float* out = (float*)d_out;

  const int D = 1024;
  const int M = in_sizes[0] / D;  // B*S = 32768

  // workspace layout (bytes): xb/ctx [M*1024 bf16] | wqkvT [3M bf16] | woT [1M bf16]
  //                           | Qb | Kb | Vb [each M*1024 bf16]   total ~264 MB
  char* ws = (char*)d_ws;
  unsigned short* xb    = (unsigned short*)ws;
  unsigned short* wqkvT = (unsigned short*)(ws + (size_t)M * 1024 * 2);
  unsigned short* woT   = wqkvT + (size_t)3 * 1024 * 1024;
  unsigned short* Qb    = woT + (size_t)1024 * 1024;
  unsigned short* Kb    = Qb + (size_t)M * 1024;
  unsigned short* Vb    = Kb + (size_t)M * 1024;
  unsigned short* ctx   = xb;  // reuse: x no longer needed after QKV GEMM

  cvt_x<<<2048, 256, 0, stream>>>(x, xb, M * D / 4);
  cvt_w<<<dim3(16, 16, 4), 256, 0, stream>>>(wq, wk, wv, wo, wqkvT, woT);
  gemm_bt<0><<<(M / 128) * (3072 / 128), 256, 0, stream>>>(
      xb, wqkvT, bq, bk, bv, Qb, Kb, Vb, nullptr, 3072, 1024);
  attn<<<(M / 64) * 16, 256, 0, stream>>>(Qb, Kb, Vb, ctx);
  gemm_bt<1><<<(M / 128) * (1024 / 128), 256, 0, stream>>>(
      ctx, woT, bo, nullptr, nullptr, nullptr, nullptr, nullptr, out, 1024, 1024);
}

// Round 2
// 428.538 us; speedup vs baseline: 1.1450x; 1.1450x over previous
//
#include <hip/hip_runtime.h>
#include <cstdint>
#include <math.h>

typedef float f32x4 __attribute__((ext_vector_type(4)));
typedef __bf16 bf16x8 __attribute__((ext_vector_type(8)));
typedef unsigned short u16x8 __attribute__((ext_vector_type(8)));
typedef unsigned short u16x4 __attribute__((ext_vector_type(4)));

typedef __attribute__((address_space(1))) const void* gas_cvptr;
typedef __attribute__((address_space(3))) void* las_vptr;

#define WAITV8 asm volatile("s_waitcnt vmcnt(8)" ::: "memory")
#define WAITV4 asm volatile("s_waitcnt vmcnt(4)" ::: "memory")
#define WAITV0 asm volatile("s_waitcnt vmcnt(0)" ::: "memory")
#define WAITL0 asm volatile("s_waitcnt lgkmcnt(0)" ::: "memory")
#define BAR()  __builtin_amdgcn_s_barrier()

__device__ __forceinline__ unsigned short f32_to_bf16(float f) {
  uint32_t u = __builtin_bit_cast(uint32_t, f);
  u += 0x7FFFu + ((u >> 16) & 1u);   // round-to-nearest-even
  return (unsigned short)(u >> 16);
}

__device__ __forceinline__ bf16x8 ld_bf16x8(const unsigned short* p) {
  return __builtin_bit_cast(bf16x8, *(const u16x8*)p);
}

// ---------------- convert x: f32 -> bf16 ----------------
__global__ void cvt_x(const float* __restrict__ x, unsigned short* __restrict__ xb, int n4) {
  int stride = gridDim.x * blockDim.x;
  for (int i = blockIdx.x * blockDim.x + threadIdx.x; i < n4; i += stride) {
    float4 v = ((const float4*)x)[i];
    u16x4 o = { f32_to_bf16(v.x), f32_to_bf16(v.y), f32_to_bf16(v.z), f32_to_bf16(v.w) };
    ((u16x4*)xb)[i] = o;
  }
}

// ------------- transpose weights [K][N] f32 -> [N][K] bf16 -------------
__global__ void cvt_w(const float* __restrict__ wq, const float* __restrict__ wk,
                      const float* __restrict__ wv, const float* __restrict__ wo,
                      unsigned short* __restrict__ wqkvT, unsigned short* __restrict__ woT) {
  const int z = blockIdx.z;
  const float* __restrict__ w = (z == 0) ? wq : (z == 1) ? wk : (z == 2) ? wv : wo;
  unsigned short* __restrict__ out = (z < 3) ? (wqkvT + (size_t)z * 1024 * 1024) : woT;
  __shared__ float tile[64][65];
  const int r0 = blockIdx.y * 64;  // k dim
  const int c0 = blockIdx.x * 64;  // n dim
  const int t = threadIdx.x;
#pragma unroll
  for (int i = 0; i < 4; i++) {
    int row = (t >> 4) + i * 16;
    int col = (t & 15) * 4;
    float4 v = *(const float4*)&w[(size_t)(r0 + row) * 1024 + c0 + col];
    tile[row][col] = v.x; tile[row][col + 1] = v.y;
    tile[row][col + 2] = v.z; tile[row][col + 3] = v.w;
  }
  __syncthreads();
#pragma unroll
  for (int i = 0; i < 2; i++) {
    int nr = (t >> 3) + i * 32;
    int kc = (t & 7) * 8;
    u16x8 o;
#pragma unroll
    for (int j = 0; j < 8; j++) o[j] = f32_to_bf16(tile[kc + j][nr]);
    *(u16x8*)&out[(size_t)(c0 + nr) * 1024 + r0 + kc] = o;
  }
}

// ============ 256x256-tile deep-pipelined GEMM: C = A[M][K] @ Bt[N][K]^T ============
// 512 threads = 8 waves (2 wm x 4 wn); wave tile 128x64; BK=32, 4 K-tile LDS buffers;
// counted vmcnt(8) keeps 2 tiles of global_load_lds in flight across barriers.
// EPI=0: scatter bf16 to Q/K/V [B][H][S][DH] + bias.  EPI=1: f32 gelu(acc+bias).
template <int EPI>
__global__ __launch_bounds__(512, 2) void gemm256(
    const unsigned short* __restrict__ A, const unsigned short* __restrict__ Bt,
    const float* __restrict__ b0, const float* __restrict__ b1, const float* __restrict__ b2,
    unsigned short* __restrict__ Qb, unsigned short* __restrict__ Kb, unsigned short* __restrict__ Vb,
    float* __restrict__ Out, int Ncols, int K) {
  __shared__ __align__(16) unsigned short As[4][256][32];
  __shared__ __align__(16) unsigned short Bs[4][256][32];
  const int NT = K >> 5;
  const int nb = Ncols >> 8;
  // XCD-aware swizzle (nwg % 8 == 0 for all our launches)
  const int nwg = gridDim.x;
  const int cpx = nwg >> 3;
  const int bid = blockIdx.x;
  const int wg = (bid & 7) * cpx + (bid >> 3);
  const int tm = wg / nb, tn = wg % nb;
  const int rowBase = tm << 8, colBase = tn << 8;
  const int t = threadIdx.x;
  const int lane = t & 63;
  const int w = t >> 6;
  const int li = lane & 15, lg = lane >> 4;
  const int wm = w >> 2, wn = w & 3;
  const int aRow0 = wm * 128;   // wave's A rows within tile
  const int bRow0 = wn * 64;    // wave's Bt rows (= C cols) within tile

  // staging: 1024 chunks of 16B per matrix per K-tile; 2 chunks/thread
  const int c0 = t, c1 = t + 512;
  const int r0s = c0 >> 2, s0s = c0 & 3;
  const int r1s = c1 >> 2, s1s = c1 & 3;
  const unsigned short* gA0 = A + (size_t)(rowBase + r0s) * K + s0s * 8;
  const unsigned short* gA1 = A + (size_t)(rowBase + r1s) * K + s1s * 8;
  const unsigned short* gB0 = Bt + (size_t)(colBase + r0s) * K + s0s * 8;
  const unsigned short* gB1 = Bt + (size_t)(colBase + r1s) * K + s1s * 8;

#define STAGE_A(tile_) do { int b_ = (tile_) & 3; int kt_ = (tile_) << 5;                     \
    __builtin_amdgcn_global_load_lds((gas_cvptr)(gA0 + kt_),                                  \
        (las_vptr)(&As[b_][0][0] + c0 * 8), 16, 0, 0);                                        \
    __builtin_amdgcn_global_load_lds((gas_cvptr)(gA1 + kt_),                                  \
        (las_vptr)(&As[b_][0][0] + c1 * 8), 16, 0, 0); } while (0)
#define STAGE_B(tile_) do { int b_ = (tile_) & 3; int kt_ = (tile_) << 5;                     \
    __builtin_amdgcn_global_load_lds((gas_cvptr)(gB0 + kt_),                                  \
        (las_vptr)(&Bs[b_][0][0] + c0 * 8), 16, 0, 0);                                        \
    __builtin_amdgcn_global_load_lds((gas_cvptr)(gB1 + kt_),                                  \
        (las_vptr)(&Bs[b_][0][0] + c1 * 8), 16, 0, 0); } while (0)

  // prologue: stage tiles 0,1,2 (tile-major queue order), land tile 0
  STAGE_A(0); STAGE_B(0);
  STAGE_A(1); STAGE_B(1);
  STAGE_A(2); STAGE_B(2);
  WAITV8;
  BAR();

  f32x4 acc[8][4] = {};
  bf16x8 af[4], bfr[4];

  for (int tt = 0; tt < NT; ++tt) {
    const unsigned short* ab = &As[tt & 3][0][0];
    const unsigned short* bb = &Bs[tt & 3][0][0];
    // ---- phase A: quadrant m0-3 x n0-3 ----
#pragma unroll
    for (int m = 0; m < 4; m++) af[m] = ld_bf16x8(ab + (aRow0 + m * 16 + li) * 32 + lg * 8);
#pragma unroll
    for (int n = 0; n < 4; n++) bfr[n] = ld_bf16x8(bb + (bRow0 + n * 16 + li) * 32 + lg * 8);
    if (tt + 3 < NT) STAGE_A(tt + 3);
    BAR();
    WAITL0;
    __builtin_amdgcn_s_setprio(1);
#pragma unroll
    for (int m = 0; m < 4; m++)
#pragma unroll
      for (int n = 0; n < 4; n++)
        acc[m][n] = __builtin_amdgcn_mfma_f32_16x16x32_bf16(af[m], bfr[n], acc[m][n], 0, 0, 0);
    __builtin_amdgcn_s_setprio(0);
    BAR();
    // ---- phase B: quadrant m4-7 x n0-3 (B frags reused from regs) ----
#pragma unroll
    for (int m = 0; m < 4; m++)
      af[m] = ld_bf16x8(ab + (aRow0 + 64 + m * 16 + li) * 32 + lg * 8);
    if (tt + 3 < NT) STAGE_B(tt + 3);
    BAR();
    WAITL0;
    __builtin_amdgcn_s_setprio(1);
#pragma unroll
    for (int m = 0; m < 4; m++)
#pragma unroll
      for (int n = 0; n < 4; n++)
        acc[4 + m][n] = __builtin_amdgcn_mfma_f32_16x16x32_bf16(af[m], bfr[n], acc[4 + m][n], 0, 0, 0);
    __builtin_amdgcn_s_setprio(0);
    // ---- per-tile checkpoint: tile tt+1 must be landed; tiles tt+2,tt+3 stay in flight ----
    if (tt <= NT - 4)      WAITV8;
    else if (tt == NT - 3) WAITV4;
    else                   WAITV0;
    BAR();
  }
#undef STAGE_A
#undef STAGE_B

  if (EPI == 0) {
    const int part = colBase >> 10;  // 0=Q 1=K 2=V (256 | 1024 so uniform per block)
    const float* __restrict__ bias = (part == 0) ? b0 : (part == 1) ? b1 : b2;
    unsigned short* __restrict__ dst = (part == 0) ? Qb : (part == 1) ? Kb : Vb;
#pragma unroll
    for (int mi = 0; mi < 8; mi++) {
      const int rowb = rowBase + aRow0 + mi * 16 + lg * 4;
#pragma unroll
      for (int r = 0; r < 4; r++) {
        const int row = rowb + r;
        const int b = row >> 6, s = row & 63;
#pragma unroll
        for (int n = 0; n < 4; n++) {
          const int col = colBase + bRow0 + n * 16 + li;
          const int within = col & 1023;
          const int h = within >> 6, dh = within & 63;
          float v = acc[mi][n][r] + bias[within];
          dst[(size_t)((b * 16 + h) * 64 + s) * 64 + dh] = f32_to_bf16(v);
        }
      }
    }
  } else {
#pragma unroll
    for (int mi = 0; mi < 8; mi++) {
      const int rowb = rowBase + aRow0 + mi * 16 + lg * 4;
#pragma unroll
      for (int r = 0; r < 4; r++) {
#pragma unroll
        for (int n = 0; n < 4; n++) {
          const int col = colBase + bRow0 + n * 16 + li;
          float v = acc[mi][n][r] + b0[col];
          v = 0.5f * v * (1.0f + erff(v * 0.70710678118654752f));
          Out[(size_t)(rowb + r) * 1024 + col] = v;
        }
      }
    }
  }
}

// ---------------- attention per (b,h): 64x64, softmax, PV ----------------
__global__ __launch_bounds__(256) void attn(
    const unsigned short* __restrict__ Qb, const unsigned short* __restrict__ Kb,
    const unsigned short* __restrict__ Vb, unsigned short* __restrict__ ctx) {
  __shared__ __align__(16) unsigned short Qs[64][72];
  __shared__ __align__(16) unsigned short Ks[64][72];
  __shared__ __align__(16) unsigned short Vt[64][72];   // transposed: [dh][s]
  __shared__ __align__(16) unsigned short Ps[64][72];
  const int bh = blockIdx.x;
  const int b = bh >> 4, h = bh & 15;
  const int t = threadIdx.x, lane = t & 63, w = t >> 6;
  const int li = lane & 15, lg = lane >> 4;
  const unsigned short* __restrict__ Qg = Qb + (size_t)bh * 4096;
  const unsigned short* __restrict__ Kg = Kb + (size_t)bh * 4096;
  const unsigned short* __restrict__ Vg = Vb + (size_t)bh * 4096;

#pragma unroll
  for (int i = 0; i < 2; i++) {
    const int c = t + i * 256;
    const int row = c >> 3, col8 = (c & 7) * 8;
    *(u16x8*)&Qs[row][col8] = *(const u16x8*)&Qg[row * 64 + col8];
    *(u16x8*)&Ks[row][col8] = *(const u16x8*)&Kg[row * 64 + col8];
    u16x8 v = *(const u16x8*)&Vg[row * 64 + col8];
#pragma unroll
    for (int j = 0; j < 8; j++) Vt[col8 + j][row] = v[j];
  }
  __syncthreads();

  f32x4 sc[4] = {};
#pragma unroll
  for (int ks = 0; ks < 2; ks++) {
    bf16x8 qa = ld_bf16x8(&Qs[w * 16 + li][ks * 32 + lg * 8]);
#pragma unroll
    for (int n = 0; n < 4; n++) {
      bf16x8 kf = ld_bf16x8(&Ks[n * 16 + li][ks * 32 + lg * 8]);
      sc[n] = __builtin_amdgcn_mfma_f32_16x16x32_bf16(qa, kf, sc[n], 0, 0, 0);
    }
  }

#pragma unroll
  for (int r = 0; r < 4; r++) {
    float v0 = sc[0][r] * 0.03125f, v1 = sc[1][r] * 0.03125f;
    float v2 = sc[2][r] * 0.03125f, v3 = sc[3][r] * 0.03125f;
    float mx = fmaxf(fmaxf(v0, v1), fmaxf(v2, v3));
#pragma unroll
    for (int off = 1; off < 16; off <<= 1) mx = fmaxf(mx, __shfl_xor(mx, off, 64));
    float e0 = __expf(v0 - mx), e1 = __expf(v1 - mx);
    float e2 = __expf(v2 - mx), e3 = __expf(v3 - mx);
    float sum = e0 + e1 + e2 + e3;
#pragma unroll
    for (int off = 1; off < 16; off <<= 1) sum += __shfl_xor(sum, off, 64);
    float is = 1.0f / sum;
    const int q = w * 16 + lg * 4 + r;
    Ps[q][0 * 16 + li] = f32_to_bf16(e0 * is);
    Ps[q][1 * 16 + li] = f32_to_bf16(e1 * is);
    Ps[q][2 * 16 + li] = f32_to_bf16(e2 * is);
    Ps[q][3 * 16 + li] = f32_to_bf16(e3 * is);
  }
  __syncthreads();

  f32x4 oc[4] = {};
#pragma unroll
  for (int ks = 0; ks < 2; ks++) {
    bf16x8 pa = ld_bf16x8(&Ps[w * 16 + li][ks * 32 + lg * 8]);
#pragma unroll
    for (int n = 0; n < 4; n++) {
      bf16x8 vf = ld_bf16x8(&Vt[n * 16 + li][ks * 32 + lg * 8]);
      oc[n] = __builtin_amdgcn_mfma_f32_16x16x32_bf16(pa, vf, oc[n], 0, 0, 0);
    }
  }
#pragma unroll
  for (int n = 0; n < 4; n++)
#pragma unroll
    for (int r = 0; r < 4; r++)
      ctx[(size_t)(b * 64 + w * 16 + lg * 4 + r) * 1024 + h * 64 + n * 16 + li] =
          f32_to_bf16(oc[n][r]);
}

extern "C" void kernel_launch(void* const* d_in, const int* in_sizes, int n_in,
                              void* d_out, int out_size, void* d_ws, size_t ws_size,
                              hipStream_t stream) {
  const float* x  = (const float*)d_in[0];
  const float* wq = (const float*)d_in[1];
  const float* bq = (const float*)d_in[2];
  const float* wk = (const float*)d_in[3];
  const float* bk = (const float*)d_in[4];
  const float* wv = (const float*)d_in[5];
  const float* bv = (const float*)d_in[6];
  const float* wo = (const float*)d_in[7];
  const float* bo = (const float*)d_in[8];
  float* out = (float*)d_out;

  const int D = 1024;
  const int M = in_sizes[0] / D;  // B*S = 32768

  char* ws = (char*)d_ws;
  unsigned short* xb    = (unsigned short*)ws;
  unsigned short* wqkvT = (unsigned short*)(ws + (size_t)M * 1024 * 2);
  unsigned short* woT   = wqkvT + (size_t)3 * 1024 * 1024;
  unsigned short* Qb    = woT + (size_t)1024 * 1024;
  unsigned short* Kb    = Qb + (size_t)M * 1024;
  unsigned short* Vb    = Kb + (size_t)M * 1024;
  unsigned short* ctx   = xb;  // reuse: x no longer needed after QKV GEMM

  cvt_x<<<2048, 256, 0, stream>>>(x, xb, M * D / 4);
  cvt_w<<<dim3(16, 16, 4), 256, 0, stream>>>(wq, wk, wv, wo, wqkvT, woT);
  gemm256<0><<<(M / 256) * (3072 / 256), 512, 0, stream>>>(
      xb, wqkvT, bq, bk, bv, Qb, Kb, Vb, nullptr, 3072, 1024);
  attn<<<(M / 64) * 16, 256, 0, stream>>>(Qb, Kb, Vb, ctx);
  gemm256<1><<<(M / 256) * (1024 / 256), 512, 0, stream>>>(
      ctx, woT, bo, nullptr, nullptr, nullptr, nullptr, nullptr, out, 1024, 1024);
}

// Round 3
// 421.523 us; speedup vs baseline: 1.1641x; 1.0166x over previous
//
#include <hip/hip_runtime.h>
#include <cstdint>
#include <math.h>

typedef float f32x4 __attribute__((ext_vector_type(4)));
typedef __bf16 bf16x8 __attribute__((ext_vector_type(8)));
typedef unsigned short u16x8 __attribute__((ext_vector_type(8)));
typedef unsigned short u16x4 __attribute__((ext_vector_type(4)));

typedef __attribute__((address_space(1))) const void* gas_cvptr;
typedef __attribute__((address_space(3))) void* las_vptr;

#define WAITV8 asm volatile("s_waitcnt vmcnt(8)" ::: "memory")
#define WAITV4 asm volatile("s_waitcnt vmcnt(4)" ::: "memory")
#define WAITV0 asm volatile("s_waitcnt vmcnt(0)" ::: "memory")
#define WAITL0 asm volatile("s_waitcnt lgkmcnt(0)" ::: "memory")
#define BAR()  __builtin_amdgcn_s_barrier()

__device__ __forceinline__ unsigned short f32_to_bf16(float f) {
  uint32_t u = __builtin_bit_cast(uint32_t, f);
  u += 0x7FFFu + ((u >> 16) & 1u);   // round-to-nearest-even
  return (unsigned short)(u >> 16);
}

__device__ __forceinline__ bf16x8 ld_bf16x8(const unsigned short* p) {
  return __builtin_bit_cast(bf16x8, *(const u16x8*)p);
}

// ---------------- convert x: f32 -> bf16 ----------------
__global__ void cvt_x(const float* __restrict__ x, unsigned short* __restrict__ xb, int n4) {
  int stride = gridDim.x * blockDim.x;
  for (int i = blockIdx.x * blockDim.x + threadIdx.x; i < n4; i += stride) {
    float4 v = ((const float4*)x)[i];
    u16x4 o = { f32_to_bf16(v.x), f32_to_bf16(v.y), f32_to_bf16(v.z), f32_to_bf16(v.w) };
    ((u16x4*)xb)[i] = o;
  }
}

// ------------- transpose weights [K][N] f32 -> [N][K] bf16 -------------
__global__ void cvt_w(const float* __restrict__ wq, const float* __restrict__ wk,
                      const float* __restrict__ wv, const float* __restrict__ wo,
                      unsigned short* __restrict__ wqkvT, unsigned short* __restrict__ woT) {
  const int z = blockIdx.z;
  const float* __restrict__ w = (z == 0) ? wq : (z == 1) ? wk : (z == 2) ? wv : wo;
  unsigned short* __restrict__ out = (z < 3) ? (wqkvT + (size_t)z * 1024 * 1024) : woT;
  __shared__ float tile[64][65];
  const int r0 = blockIdx.y * 64;  // k dim
  const int c0 = blockIdx.x * 64;  // n dim
  const int t = threadIdx.x;
#pragma unroll
  for (int i = 0; i < 4; i++) {
    int row = (t >> 4) + i * 16;
    int col = (t & 15) * 4;
    float4 v = *(const float4*)&w[(size_t)(r0 + row) * 1024 + c0 + col];
    tile[row][col] = v.x; tile[row][col + 1] = v.y;
    tile[row][col + 2] = v.z; tile[row][col + 3] = v.w;
  }
  __syncthreads();
#pragma unroll
  for (int i = 0; i < 2; i++) {
    int nr = (t >> 3) + i * 32;
    int kc = (t & 7) * 8;
    u16x8 o;
#pragma unroll
    for (int j = 0; j < 8; j++) o[j] = f32_to_bf16(tile[kc + j][nr]);
    *(u16x8*)&out[(size_t)(c0 + nr) * 1024 + r0 + kc] = o;
  }
}

// ============ 256x256-tile deep-pipelined GEMM: C = A[M][K] @ Bt[N][K]^T ============
// 512 threads = 8 waves (2 wm x 4 wn); wave tile 128x64; BK=32, 4 K-tile LDS buffers;
// counted vmcnt(8) keeps 2 tiles of global_load_lds in flight across barriers.
// LDS bank-conflict fix: physical 16B-chunk pc = lc ^ ((row>>1)&3), applied as
// pre-swizzled GLOBAL source (global_load_lds dest stays linear) + swizzled read.
template <int EPI>
__global__ __launch_bounds__(512, 2) void gemm256(
    const unsigned short* __restrict__ A, const unsigned short* __restrict__ Bt,
    const float* __restrict__ b0, const float* __restrict__ b1, const float* __restrict__ b2,
    unsigned short* __restrict__ Qb, unsigned short* __restrict__ Kb, unsigned short* __restrict__ Vb,
    float* __restrict__ Out, int Ncols, int K) {
  __shared__ __align__(16) unsigned short As[4][256][32];
  __shared__ __align__(16) unsigned short Bs[4][256][32];
  const int NT = K >> 5;
  const int nb = Ncols >> 8;
  // XCD-aware swizzle (nwg % 8 == 0 for all our launches)
  const int nwg = gridDim.x;
  const int cpx = nwg >> 3;
  const int bid = blockIdx.x;
  const int wg = (bid & 7) * cpx + (bid >> 3);
  const int tm = wg / nb, tn = wg % nb;
  const int rowBase = tm << 8, colBase = tn << 8;
  const int t = threadIdx.x;
  const int lane = t & 63;
  const int w = t >> 6;
  const int li = lane & 15, lg = lane >> 4;
  const int wm = w >> 2, wn = w & 3;
  const int aRow0 = wm * 128;   // wave's A rows within tile
  const int bRow0 = wn * 64;    // wave's Bt rows (= C cols) within tile
  // swizzled k-offset for fragment reads: (row>>1)&3 == (li>>1)&3 for all our rows
  const int koff = ((lg ^ ((li >> 1) & 3)) << 3);

  // staging: 1024 chunks of 16B per matrix per K-tile; 2 chunks/thread.
  // thread's chunk c lands at physical (row=c>>2, pc=c&3); source = logical
  // chunk lc = pc ^ ((row>>1)&3) of that row.
  const int c0 = t, c1 = t + 512;
  const int r0s = c0 >> 2, r1s = c1 >> 2;
  const int l0s = (c0 & 3) ^ ((r0s >> 1) & 3);
  const int l1s = (c1 & 3) ^ ((r1s >> 1) & 3);
  const unsigned short* gA0 = A + (size_t)(rowBase + r0s) * K + l0s * 8;
  const unsigned short* gA1 = A + (size_t)(rowBase + r1s) * K + l1s * 8;
  const unsigned short* gB0 = Bt + (size_t)(colBase + r0s) * K + l0s * 8;
  const unsigned short* gB1 = Bt + (size_t)(colBase + r1s) * K + l1s * 8;

#define STAGE_A(tile_) do { int b_ = (tile_) & 3; int kt_ = (tile_) << 5;                     \
    __builtin_amdgcn_global_load_lds((gas_cvptr)(gA0 + kt_),                                  \
        (las_vptr)(&As[b_][0][0] + c0 * 8), 16, 0, 0);                                        \
    __builtin_amdgcn_global_load_lds((gas_cvptr)(gA1 + kt_),                                  \
        (las_vptr)(&As[b_][0][0] + c1 * 8), 16, 0, 0); } while (0)
#define STAGE_B(tile_) do { int b_ = (tile_) & 3; int kt_ = (tile_) << 5;                     \
    __builtin_amdgcn_global_load_lds((gas_cvptr)(gB0 + kt_),                                  \
        (las_vptr)(&Bs[b_][0][0] + c0 * 8), 16, 0, 0);                                        \
    __builtin_amdgcn_global_load_lds((gas_cvptr)(gB1 + kt_),                                  \
        (las_vptr)(&Bs[b_][0][0] + c1 * 8), 16, 0, 0); } while (0)

  // prologue: stage tiles 0,1,2 (tile-major queue order), land tile 0
  STAGE_A(0); STAGE_B(0);
  STAGE_A(1); STAGE_B(1);
  STAGE_A(2); STAGE_B(2);
  WAITV8;
  BAR();

  f32x4 acc[8][4] = {};
  bf16x8 af[4], bfr[4];

  for (int tt = 0; tt < NT; ++tt) {
    const unsigned short* ab = &As[tt & 3][0][0];
    const unsigned short* bb = &Bs[tt & 3][0][0];
    // ---- phase A: quadrant m0-3 x n0-3 ----
#pragma unroll
    for (int m = 0; m < 4; m++) af[m] = ld_bf16x8(ab + (aRow0 + m * 16 + li) * 32 + koff);
#pragma unroll
    for (int n = 0; n < 4; n++) bfr[n] = ld_bf16x8(bb + (bRow0 + n * 16 + li) * 32 + koff);
    if (tt + 3 < NT) STAGE_A(tt + 3);
    BAR();
    WAITL0;
    __builtin_amdgcn_s_setprio(1);
#pragma unroll
    for (int m = 0; m < 4; m++)
#pragma unroll
      for (int n = 0; n < 4; n++)
        acc[m][n] = __builtin_amdgcn_mfma_f32_16x16x32_bf16(af[m], bfr[n], acc[m][n], 0, 0, 0);
    __builtin_amdgcn_s_setprio(0);
    BAR();
    // ---- phase B: quadrant m4-7 x n0-3 (B frags reused from regs) ----
#pragma unroll
    for (int m = 0; m < 4; m++)
      af[m] = ld_bf16x8(ab + (aRow0 + 64 + m * 16 + li) * 32 + koff);
    if (tt + 3 < NT) STAGE_B(tt + 3);
    BAR();
    WAITL0;
    __builtin_amdgcn_s_setprio(1);
#pragma unroll
    for (int m = 0; m < 4; m++)
#pragma unroll
      for (int n = 0; n < 4; n++)
        acc[4 + m][n] = __builtin_amdgcn_mfma_f32_16x16x32_bf16(af[m], bfr[n], acc[4 + m][n], 0, 0, 0);
    __builtin_amdgcn_s_setprio(0);
    // ---- per-tile checkpoint: tile tt+1 must be landed; tiles tt+2,tt+3 stay in flight ----
    if (tt <= NT - 4)      WAITV8;
    else if (tt == NT - 3) WAITV4;
    else                   WAITV0;
    BAR();
  }
#undef STAGE_A
#undef STAGE_B

  if (EPI == 0) {
    const int part = colBase >> 10;  // 0=Q 1=K 2=V (256 | 1024 so uniform per block)
    const float* __restrict__ bias = (part == 0) ? b0 : (part == 1) ? b1 : b2;
    unsigned short* __restrict__ dst = (part == 0) ? Qb : (part == 1) ? Kb : Vb;
#pragma unroll
    for (int mi = 0; mi < 8; mi++) {
      const int rowb = rowBase + aRow0 + mi * 16 + lg * 4;
#pragma unroll
      for (int r = 0; r < 4; r++) {
        const int row = rowb + r;
        const int b = row >> 6, s = row & 63;
#pragma unroll
        for (int n = 0; n < 4; n++) {
          const int col = colBase + bRow0 + n * 16 + li;
          const int within = col & 1023;
          const int h = within >> 6, dh = within & 63;
          float v = acc[mi][n][r] + bias[within];
          dst[(size_t)((b * 16 + h) * 64 + s) * 64 + dh] = f32_to_bf16(v);
        }
      }
    }
  } else {
#pragma unroll
    for (int mi = 0; mi < 8; mi++) {
      const int rowb = rowBase + aRow0 + mi * 16 + lg * 4;
#pragma unroll
      for (int r = 0; r < 4; r++) {
#pragma unroll
        for (int n = 0; n < 4; n++) {
          const int col = colBase + bRow0 + n * 16 + li;
          float v = acc[mi][n][r] + b0[col];
          v = 0.5f * v * (1.0f + erff(v * 0.70710678118654752f));
          Out[(size_t)(rowb + r) * 1024 + col] = v;
        }
      }
    }
  }
}

// ---------------- attention per (b,h): 64x64, softmax, PV ----------------
__global__ __launch_bounds__(256) void attn(
    const unsigned short* __restrict__ Qb, const unsigned short* __restrict__ Kb,
    const unsigned short* __restrict__ Vb, unsigned short* __restrict__ ctx) {
  __shared__ __align__(16) unsigned short Qs[64][72];
  __shared__ __align__(16) unsigned short Ks[64][72];
  __shared__ __align__(16) unsigned short Vt[64][72];   // transposed: [dh][s]
  __shared__ __align__(16) unsigned short Ps[64][72];
  const int bh = blockIdx.x;
  const int b = bh >> 4, h = bh & 15;
  const int t = threadIdx.x, lane = t & 63, w = t >> 6;
  const int li = lane & 15, lg = lane >> 4;
  const unsigned short* __restrict__ Qg = Qb + (size_t)bh * 4096;
  const unsigned short* __restrict__ Kg = Kb + (size_t)bh * 4096;
  const unsigned short* __restrict__ Vg = Vb + (size_t)bh * 4096;

#pragma unroll
  for (int i = 0; i < 2; i++) {
    const int c = t + i * 256;
    const int row = c >> 3, col8 = (c & 7) * 8;
    *(u16x8*)&Qs[row][col8] = *(const u16x8*)&Qg[row * 64 + col8];
    *(u16x8*)&Ks[row][col8] = *(const u16x8*)&Kg[row * 64 + col8];
    u16x8 v = *(const u16x8*)&Vg[row * 64 + col8];
#pragma unroll
    for (int j = 0; j < 8; j++) Vt[col8 + j][row] = v[j];
  }
  __syncthreads();

  f32x4 sc[4] = {};
#pragma unroll
  for (int ks = 0; ks < 2; ks++) {
    bf16x8 qa = ld_bf16x8(&Qs[w * 16 + li][ks * 32 + lg * 8]);
#pragma unroll
    for (int n = 0; n < 4; n++) {
      bf16x8 kf = ld_bf16x8(&Ks[n * 16 + li][ks * 32 + lg * 8]);
      sc[n] = __builtin_amdgcn_mfma_f32_16x16x32_bf16(qa, kf, sc[n], 0, 0, 0);
    }
  }

#pragma unroll
  for (int r = 0; r < 4; r++) {
    float v0 = sc[0][r] * 0.03125f, v1 = sc[1][r] * 0.03125f;
    float v2 = sc[2][r] * 0.03125f, v3 = sc[3][r] * 0.03125f;
    float mx = fmaxf(fmaxf(v0, v1), fmaxf(v2, v3));
#pragma unroll
    for (int off = 1; off < 16; off <<= 1) mx = fmaxf(mx, __shfl_xor(mx, off, 64));
    float e0 = __expf(v0 - mx), e1 = __expf(v1 - mx);
    float e2 = __expf(v2 - mx), e3 = __expf(v3 - mx);
    float sum = e0 + e1 + e2 + e3;
#pragma unroll
    for (int off = 1; off < 16; off <<= 1) sum += __shfl_xor(sum, off, 64);
    float is = 1.0f / sum;
    const int q = w * 16 + lg * 4 + r;
    Ps[q][0 * 16 + li] = f32_to_bf16(e0 * is);
    Ps[q][1 * 16 + li] = f32_to_bf16(e1 * is);
    Ps[q][2 * 16 + li] = f32_to_bf16(e2 * is);
    Ps[q][3 * 16 + li] = f32_to_bf16(e3 * is);
  }
  __syncthreads();

  f32x4 oc[4] = {};
#pragma unroll
  for (int ks = 0; ks < 2; ks++) {
    bf16x8 pa = ld_bf16x8(&Ps[w * 16 + li][ks * 32 + lg * 8]);
#pragma unroll
    for (int n = 0; n < 4; n++) {
      bf16x8 vf = ld_bf16x8(&Vt[n * 16 + li][ks * 32 + lg * 8]);
      oc[n] = __builtin_amdgcn_mfma_f32_16x16x32_bf16(pa, vf, oc[n], 0, 0, 0);
    }
  }
#pragma unroll
  for (int n = 0; n < 4; n++)
#pragma unroll
    for (int r = 0; r < 4; r++)
      ctx[(size_t)(b * 64 + w * 16 + lg * 4 + r) * 1024 + h * 64 + n * 16 + li] =
          f32_to_bf16(oc[n][r]);
}

extern "C" void kernel_launch(void* const* d_in, const int* in_sizes, int n_in,
                              void* d_out, int out_size, void* d_ws, size_t ws_size,
                              hipStream_t stream) {
  const float* x  = (const float*)d_in[0];
  const float* wq = (const float*)d_in[1];
  const float* bq = (const float*)d_in[2];
  const float* wk = (const float*)d_in[3];
  const float* bk = (const float*)d_in[4];
  const float* wv = (const float*)d_in[5];
  const float* bv = (const float*)d_in[6];
  const float* wo = (const float*)d_in[7];
  const float* bo = (const float*)d_in[8];
  float* out = (float*)d_out;

  const int D = 1024;
  const int M = in_sizes[0] / D;  // B*S = 32768

  char* ws = (char*)d_ws;
  unsigned short* xb    = (unsigned short*)ws;
  unsigned short* wqkvT = (unsigned short*)(ws + (size_t)M * 1024 * 2);
  unsigned short* woT   = wqkvT + (size_t)3 * 1024 * 1024;
  unsigned short* Qb    = woT + (size_t)1024 * 1024;
  unsigned short* Kb    = Qb + (size_t)M * 1024;
  unsigned short* Vb    = Kb + (size_t)M * 1024;
  unsigned short* ctx   = xb;  // reuse: x no longer needed after QKV GEMM

  cvt_x<<<2048, 256, 0, stream>>>(x, xb, M * D / 4);
  cvt_w<<<dim3(16, 16, 4), 256, 0, stream>>>(wq, wk, wv, wo, wqkvT, woT);
  gemm256<0><<<(M / 256) * (3072 / 256), 512, 0, stream>>>(
      xb, wqkvT, bq, bk, bv, Qb, Kb, Vb, nullptr, 3072, 1024);
  attn<<<(M / 64) * 16, 256, 0, stream>>>(Qb, Kb, Vb, ctx);
  gemm256<1><<<(M / 256) * (1024 / 256), 512, 0, stream>>>(
      ctx, woT, bo, nullptr, nullptr, nullptr, nullptr, nullptr, out, 1024, 1024);
}

// Round 4
// 410.446 us; speedup vs baseline: 1.1955x; 1.0270x over previous
//
#include <hip/hip_runtime.h>
#include <cstdint>
#include <math.h>

typedef float f32x4 __attribute__((ext_vector_type(4)));
typedef __bf16 bf16x8 __attribute__((ext_vector_type(8)));
typedef unsigned short u16x8 __attribute__((ext_vector_type(8)));
typedef unsigned short u16x4 __attribute__((ext_vector_type(4)));

typedef __attribute__((address_space(1))) const void* gas_cvptr;
typedef __attribute__((address_space(3))) void* las_vptr;

#define WAITV8 asm volatile("s_waitcnt vmcnt(8)" ::: "memory")
#define WAITV4 asm volatile("s_waitcnt vmcnt(4)" ::: "memory")
#define WAITV0 asm volatile("s_waitcnt vmcnt(0)" ::: "memory")
#define WAITL0 asm volatile("s_waitcnt lgkmcnt(0)" ::: "memory")
#define WAITL4 asm volatile("s_waitcnt lgkmcnt(4)" ::: "memory")
#define SB()   __builtin_amdgcn_sched_barrier(0)
#define BAR()  __builtin_amdgcn_s_barrier()

__device__ __forceinline__ unsigned short f32_to_bf16(float f) {
  uint32_t u = __builtin_bit_cast(uint32_t, f);
  u += 0x7FFFu + ((u >> 16) & 1u);   // round-to-nearest-even
  return (unsigned short)(u >> 16);
}

__device__ __forceinline__ bf16x8 ld_bf16x8(const unsigned short* p) {
  return __builtin_bit_cast(bf16x8, *(const u16x8*)p);
}

// ---------------- convert x: f32 -> bf16 ----------------
__global__ void cvt_x(const float* __restrict__ x, unsigned short* __restrict__ xb, int n4) {
  int stride = gridDim.x * blockDim.x;
  for (int i = blockIdx.x * blockDim.x + threadIdx.x; i < n4; i += stride) {
    float4 v = ((const float4*)x)[i];
    u16x4 o = { f32_to_bf16(v.x), f32_to_bf16(v.y), f32_to_bf16(v.z), f32_to_bf16(v.w) };
    ((u16x4*)xb)[i] = o;
  }
}

// ------------- transpose weights [K][N] f32 -> [N][K] bf16 -------------
__global__ void cvt_w(const float* __restrict__ wq, const float* __restrict__ wk,
                      const float* __restrict__ wv, const float* __restrict__ wo,
                      unsigned short* __restrict__ wqkvT, unsigned short* __restrict__ woT) {
  const int z = blockIdx.z;
  const float* __restrict__ w = (z == 0) ? wq : (z == 1) ? wk : (z == 2) ? wv : wo;
  unsigned short* __restrict__ out = (z < 3) ? (wqkvT + (size_t)z * 1024 * 1024) : woT;
  __shared__ float tile[64][65];
  const int r0 = blockIdx.y * 64;  // k dim
  const int c0 = blockIdx.x * 64;  // n dim
  const int t = threadIdx.x;
#pragma unroll
  for (int i = 0; i < 4; i++) {
    int row = (t >> 4) + i * 16;
    int col = (t & 15) * 4;
    float4 v = *(const float4*)&w[(size_t)(r0 + row) * 1024 + c0 + col];
    tile[row][col] = v.x; tile[row][col + 1] = v.y;
    tile[row][col + 2] = v.z; tile[row][col + 3] = v.w;
  }
  __syncthreads();
#pragma unroll
  for (int i = 0; i < 2; i++) {
    int nr = (t >> 3) + i * 32;
    int kc = (t & 7) * 8;
    u16x8 o;
#pragma unroll
    for (int j = 0; j < 8; j++) o[j] = f32_to_bf16(tile[kc + j][nr]);
    *(u16x8*)&out[(size_t)(c0 + nr) * 1024 + r0 + kc] = o;
  }
}

// ============ 256x256-tile deep-pipelined GEMM: C = A[M][K] @ Bt[N][K]^T ============
// 512 threads = 8 waves (2 wm x 4 wn); wave tile 128x64; BK=32, 4 K-tile LDS buffers;
// counted vmcnt(8) keeps 2 tiles of global_load_lds in flight across barriers.
// ONE barrier per K-tile; fragment reads staggered (phase-A's 8 first) with counted
// lgkmcnt(4) so phase-B read latency hides under phase-A's 16 MFMA.
// LDS bank-conflict fix: physical 16B-chunk pc = lc ^ ((row>>1)&3), pre-swizzled
// GLOBAL source (global_load_lds dest stays linear) + swizzled read offset.
template <int EPI>
__global__ __launch_bounds__(512, 2) void gemm256(
    const unsigned short* __restrict__ A, const unsigned short* __restrict__ Bt,
    const float* __restrict__ b0, const float* __restrict__ b1, const float* __restrict__ b2,
    unsigned short* __restrict__ Qb, unsigned short* __restrict__ Kb, unsigned short* __restrict__ Vb,
    float* __restrict__ Out, int Ncols, int K) {
  __shared__ __align__(16) unsigned short As[4][256][32];
  __shared__ __align__(16) unsigned short Bs[4][256][32];
  const int NT = K >> 5;
  const int nb = Ncols >> 8;
  // XCD-aware swizzle (nwg % 8 == 0 for all our launches)
  const int nwg = gridDim.x;
  const int cpx = nwg >> 3;
  const int bid = blockIdx.x;
  const int wg = (bid & 7) * cpx + (bid >> 3);
  const int tm = wg / nb, tn = wg % nb;
  const int rowBase = tm << 8, colBase = tn << 8;
  const int t = threadIdx.x;
  const int lane = t & 63;
  const int w = t >> 6;
  const int li = lane & 15, lg = lane >> 4;
  const int wm = w >> 2, wn = w & 3;
  const int aRow0 = wm * 128;   // wave's A rows within tile
  const int bRow0 = wn * 64;    // wave's Bt rows (= C cols) within tile
  // swizzled k-offset for fragment reads: (row>>1)&3 == (li>>1)&3 for all our rows
  const int koff = ((lg ^ ((li >> 1) & 3)) << 3);

  // staging: 1024 chunks of 16B per matrix per K-tile; 2 chunks/thread.
  // thread's chunk c lands at physical (row=c>>2, pc=c&3); source = logical
  // chunk lc = pc ^ ((row>>1)&3) of that row.
  const int c0 = t, c1 = t + 512;
  const int r0s = c0 >> 2, r1s = c1 >> 2;
  const int l0s = (c0 & 3) ^ ((r0s >> 1) & 3);
  const int l1s = (c1 & 3) ^ ((r1s >> 1) & 3);
  const unsigned short* gA0 = A + (size_t)(rowBase + r0s) * K + l0s * 8;
  const unsigned short* gA1 = A + (size_t)(rowBase + r1s) * K + l1s * 8;
  const unsigned short* gB0 = Bt + (size_t)(colBase + r0s) * K + l0s * 8;
  const unsigned short* gB1 = Bt + (size_t)(colBase + r1s) * K + l1s * 8;

#define STAGE_A(tile_) do { int b_ = (tile_) & 3; int kt_ = (tile_) << 5;                     \
    __builtin_amdgcn_global_load_lds((gas_cvptr)(gA0 + kt_),                                  \
        (las_vptr)(&As[b_][0][0] + c0 * 8), 16, 0, 0);                                        \
    __builtin_amdgcn_global_load_lds((gas_cvptr)(gA1 + kt_),                                  \
        (las_vptr)(&As[b_][0][0] + c1 * 8), 16, 0, 0); } while (0)
#define STAGE_B(tile_) do { int b_ = (tile_) & 3; int kt_ = (tile_) << 5;                     \
    __builtin_amdgcn_global_load_lds((gas_cvptr)(gB0 + kt_),                                  \
        (las_vptr)(&Bs[b_][0][0] + c0 * 8), 16, 0, 0);                                        \
    __builtin_amdgcn_global_load_lds((gas_cvptr)(gB1 + kt_),                                  \
        (las_vptr)(&Bs[b_][0][0] + c1 * 8), 16, 0, 0); } while (0)

  // prologue: stage tiles 0,1,2 (tile-major queue order), land tile 0
  STAGE_A(0); STAGE_B(0);
  STAGE_A(1); STAGE_B(1);
  STAGE_A(2); STAGE_B(2);
  WAITV8;
  BAR();

  f32x4 acc[8][4] = {};

  for (int tt = 0; tt < NT; ++tt) {
    const unsigned short* ab = &As[tt & 3][0][0];
    const unsigned short* bb = &Bs[tt & 3][0][0];
    // issue all 12 fragment reads; phase-A's 8 first (issue order = wait order)
    bf16x8 afA[4], bfrA[4], afB[4];
#pragma unroll
    for (int m = 0; m < 4; m++) afA[m] = ld_bf16x8(ab + (aRow0 + m * 16 + li) * 32 + koff);
#pragma unroll
    for (int n = 0; n < 4; n++) bfrA[n] = ld_bf16x8(bb + (bRow0 + n * 16 + li) * 32 + koff);
#pragma unroll
    for (int m = 0; m < 4; m++)
      afB[m] = ld_bf16x8(ab + (aRow0 + 64 + m * 16 + li) * 32 + koff);
    if (tt + 3 < NT) { STAGE_A(tt + 3); STAGE_B(tt + 3); }
    WAITL4;             // first 8 reads (afA,bfrA) landed; afB still in flight
    SB();
    __builtin_amdgcn_s_setprio(1);
#pragma unroll
    for (int m = 0; m < 4; m++)
#pragma unroll
      for (int n = 0; n < 4; n++)
        acc[m][n] = __builtin_amdgcn_mfma_f32_16x16x32_bf16(afA[m], bfrA[n], acc[m][n], 0, 0, 0);
    SB();
    WAITL0;             // afB landed
    SB();
#pragma unroll
    for (int m = 0; m < 4; m++)
#pragma unroll
      for (int n = 0; n < 4; n++)
        acc[4 + m][n] = __builtin_amdgcn_mfma_f32_16x16x32_bf16(afB[m], bfrA[n], acc[4 + m][n], 0, 0, 0);
    __builtin_amdgcn_s_setprio(0);
    // per-tile checkpoint: tile tt+1 landed; tiles tt+2,tt+3 stay in flight.
    // single barrier per tile: WAR-safe because each wave's LDS reads of the
    // buffer STAGE(tt+4) will overwrite completed before the previous barrier.
    if (tt <= NT - 4)      WAITV8;
    else if (tt == NT - 3) WAITV4;
    else                   WAITV0;
    BAR();
  }
#undef STAGE_A
#undef STAGE_B

  if (EPI == 0) {
    const int part = colBase >> 10;  // 0=Q 1=K 2=V (256 | 1024 so uniform per block)
    const float* __restrict__ bias = (part == 0) ? b0 : (part == 1) ? b1 : b2;
    unsigned short* __restrict__ dst = (part == 0) ? Qb : (part == 1) ? Kb : Vb;
#pragma unroll
    for (int mi = 0; mi < 8; mi++) {
      const int rowb = rowBase + aRow0 + mi * 16 + lg * 4;
#pragma unroll
      for (int r = 0; r < 4; r++) {
        const int row = rowb + r;
        const int b = row >> 6, s = row & 63;
#pragma unroll
        for (int n = 0; n < 4; n++) {
          const int col = colBase + bRow0 + n * 16 + li;
          const int within = col & 1023;
          const int h = within >> 6, dh = within & 63;
          float v = acc[mi][n][r] + bias[within];
          dst[(size_t)((b * 16 + h) * 64 + s) * 64 + dh] = f32_to_bf16(v);
        }
      }
    }
  } else {
#pragma unroll
    for (int mi = 0; mi < 8; mi++) {
      const int rowb = rowBase + aRow0 + mi * 16 + lg * 4;
#pragma unroll
      for (int r = 0; r < 4; r++) {
#pragma unroll
        for (int n = 0; n < 4; n++) {
          const int col = colBase + bRow0 + n * 16 + li;
          float v = acc[mi][n][r] + b0[col];
          v = 0.5f * v * (1.0f + erff(v * 0.70710678118654752f));
          Out[(size_t)(rowb + r) * 1024 + col] = v;
        }
      }
    }
  }
}

// ---------------- attention per (b,h): 64x64, softmax, PV ----------------
__global__ __launch_bounds__(256) void attn(
    const unsigned short* __restrict__ Qb, const unsigned short* __restrict__ Kb,
    const unsigned short* __restrict__ Vb, unsigned short* __restrict__ ctx) {
  __shared__ __align__(16) unsigned short Qs[64][72];
  __shared__ __align__(16) unsigned short Ks[64][72];
  __shared__ __align__(16) unsigned short Vt[64][72];   // transposed: [dh][s]
  __shared__ __align__(16) unsigned short Ps[64][72];
  const int bh = blockIdx.x;
  const int b = bh >> 4, h = bh & 15;
  const int t = threadIdx.x, lane = t & 63, w = t >> 6;
  const int li = lane & 15, lg = lane >> 4;
  const unsigned short* __restrict__ Qg = Qb + (size_t)bh * 4096;
  const unsigned short* __restrict__ Kg = Kb + (size_t)bh * 4096;
  const unsigned short* __restrict__ Vg = Vb + (size_t)bh * 4096;

#pragma unroll
  for (int i = 0; i < 2; i++) {
    const int c = t + i * 256;
    const int row = c >> 3, col8 = (c & 7) * 8;
    *(u16x8*)&Qs[row][col8] = *(const u16x8*)&Qg[row * 64 + col8];
    *(u16x8*)&Ks[row][col8] = *(const u16x8*)&Kg[row * 64 + col8];
    u16x8 v = *(const u16x8*)&Vg[row * 64 + col8];
#pragma unroll
    for (int j = 0; j < 8; j++) Vt[col8 + j][row] = v[j];
  }
  __syncthreads();

  f32x4 sc[4] = {};
#pragma unroll
  for (int ks = 0; ks < 2; ks++) {
    bf16x8 qa = ld_bf16x8(&Qs[w * 16 + li][ks * 32 + lg * 8]);
#pragma unroll
    for (int n = 0; n < 4; n++) {
      bf16x8 kf = ld_bf16x8(&Ks[n * 16 + li][ks * 32 + lg * 8]);
      sc[n] = __builtin_amdgcn_mfma_f32_16x16x32_bf16(qa, kf, sc[n], 0, 0, 0);
    }
  }

#pragma unroll
  for (int r = 0; r < 4; r++) {
    float v0 = sc[0][r] * 0.03125f, v1 = sc[1][r] * 0.03125f;
    float v2 = sc[2][r] * 0.03125f, v3 = sc[3][r] * 0.03125f;
    float mx = fmaxf(fmaxf(v0, v1), fmaxf(v2, v3));
#pragma unroll
    for (int off = 1; off < 16; off <<= 1) mx = fmaxf(mx, __shfl_xor(mx, off, 64));
    float e0 = __expf(v0 - mx), e1 = __expf(v1 - mx);
    float e2 = __expf(v2 - mx), e3 = __expf(v3 - mx);
    float sum = e0 + e1 + e2 + e3;
#pragma unroll
    for (int off = 1; off < 16; off <<= 1) sum += __shfl_xor(sum, off, 64);
    float is = 1.0f / sum;
    const int q = w * 16 + lg * 4 + r;
    Ps[q][0 * 16 + li] = f32_to_bf16(e0 * is);
    Ps[q][1 * 16 + li] = f32_to_bf16(e1 * is);
    Ps[q][2 * 16 + li] = f32_to_bf16(e2 * is);
    Ps[q][3 * 16 + li] = f32_to_bf16(e3 * is);
  }
  __syncthreads();

  f32x4 oc[4] = {};
#pragma unroll
  for (int ks = 0; ks < 2; ks++) {
    bf16x8 pa = ld_bf16x8(&Ps[w * 16 + li][ks * 32 + lg * 8]);
#pragma unroll
    for (int n = 0; n < 4; n++) {
      bf16x8 vf = ld_bf16x8(&Vt[n * 16 + li][ks * 32 + lg * 8]);
      oc[n] = __builtin_amdgcn_mfma_f32_16x16x32_bf16(pa, vf, oc[n], 0, 0, 0);
    }
  }
#pragma unroll
  for (int n = 0; n < 4; n++)
#pragma unroll
    for (int r = 0; r < 4; r++)
      ctx[(size_t)(b * 64 + w * 16 + lg * 4 + r) * 1024 + h * 64 + n * 16 + li] =
          f32_to_bf16(oc[n][r]);
}

extern "C" void kernel_launch(void* const* d_in, const int* in_sizes, int n_in,
                              void* d_out, int out_size, void* d_ws, size_t ws_size,
                              hipStream_t stream) {
  const float* x  = (const float*)d_in[0];
  const float* wq = (const float*)d_in[1];
  const float* bq = (const float*)d_in[2];
  const float* wk = (const float*)d_in[3];
  const float* bk = (const float*)d_in[4];
  const float* wv = (const float*)d_in[5];
  const float* bv = (const float*)d_in[6];
  const float* wo = (const float*)d_in[7];
  const float* bo = (const float*)d_in[8];
  float* out = (float*)d_out;

  const int D = 1024;
  const int M = in_sizes[0] / D;  // B*S = 32768

  char* ws = (char*)d_ws;
  unsigned short* xb    = (unsigned short*)ws;
  unsigned short* wqkvT = (unsigned short*)(ws + (size_t)M * 1024 * 2);
  unsigned short* woT   = wqkvT + (size_t)3 * 1024 * 1024;
  unsigned short* Qb    = woT + (size_t)1024 * 1024;
  unsigned short* Kb    = Qb + (size_t)M * 1024;
  unsigned short* Vb    = Kb + (size_t)M * 1024;
  unsigned short* ctx   = xb;  // reuse: x no longer needed after QKV GEMM

  cvt_x<<<2048, 256, 0, stream>>>(x, xb, M * D / 4);
  cvt_w<<<dim3(16, 16, 4), 256, 0, stream>>>(wq, wk, wv, wo, wqkvT, woT);
  gemm256<0><<<(M / 256) * (3072 / 256), 512, 0, stream>>>(
      xb, wqkvT, bq, bk, bv, Qb, Kb, Vb, nullptr, 3072, 1024);
  attn<<<(M / 64) * 16, 256, 0, stream>>>(Qb, Kb, Vb, ctx);
  gemm256<1><<<(M / 256) * (1024 / 256), 512, 0, stream>>>(
      ctx, woT, bo, nullptr, nullptr, nullptr, nullptr, nullptr, out, 1024, 1024);
}

// Round 5
// 409.757 us; speedup vs baseline: 1.1975x; 1.0017x over previous
//
#include <hip/hip_runtime.h>
#include <cstdint>
#include <math.h>

typedef float f32x4 __attribute__((ext_vector_type(4)));
typedef __bf16 bf16x8 __attribute__((ext_vector_type(8)));
typedef unsigned short u16x8 __attribute__((ext_vector_type(8)));
typedef unsigned short u16x4 __attribute__((ext_vector_type(4)));

typedef __attribute__((address_space(1))) const void* gas_cvptr;
typedef __attribute__((address_space(3))) void* las_vptr;

#define WAITV12 asm volatile("s_waitcnt vmcnt(12)" ::: "memory")
#define WAITV8 asm volatile("s_waitcnt vmcnt(8)" ::: "memory")
#define WAITV4 asm volatile("s_waitcnt vmcnt(4)" ::: "memory")
#define WAITV0 asm volatile("s_waitcnt vmcnt(0)" ::: "memory")
#define WAITL0 asm volatile("s_waitcnt lgkmcnt(0)" ::: "memory")
#define SB()   __builtin_amdgcn_sched_barrier(0)
#define BAR()  __builtin_amdgcn_s_barrier()

__device__ __forceinline__ unsigned short f32_to_bf16(float f) {
  uint32_t u = __builtin_bit_cast(uint32_t, f);
  u += 0x7FFFu + ((u >> 16) & 1u);   // round-to-nearest-even
  return (unsigned short)(u >> 16);
}

__device__ __forceinline__ bf16x8 ld_bf16x8(const unsigned short* p) {
  return __builtin_bit_cast(bf16x8, *(const u16x8*)p);
}

// ---------------- convert x: f32 -> bf16 ----------------
__global__ void cvt_x(const float* __restrict__ x, unsigned short* __restrict__ xb, int n4) {
  int stride = gridDim.x * blockDim.x;
  for (int i = blockIdx.x * blockDim.x + threadIdx.x; i < n4; i += stride) {
    float4 v = ((const float4*)x)[i];
    u16x4 o = { f32_to_bf16(v.x), f32_to_bf16(v.y), f32_to_bf16(v.z), f32_to_bf16(v.w) };
    ((u16x4*)xb)[i] = o;
  }
}

// ------------- transpose weights [K][N] f32 -> [N][K] bf16 -------------
__global__ void cvt_w(const float* __restrict__ wq, const float* __restrict__ wk,
                      const float* __restrict__ wv, const float* __restrict__ wo,
                      unsigned short* __restrict__ wqkvT, unsigned short* __restrict__ woT) {
  const int z = blockIdx.z;
  const float* __restrict__ w = (z == 0) ? wq : (z == 1) ? wk : (z == 2) ? wv : wo;
  unsigned short* __restrict__ out = (z < 3) ? (wqkvT + (size_t)z * 1024 * 1024) : woT;
  __shared__ float tile[64][65];
  const int r0 = blockIdx.y * 64;  // k dim
  const int c0 = blockIdx.x * 64;  // n dim
  const int t = threadIdx.x;
#pragma unroll
  for (int i = 0; i < 4; i++) {
    int row = (t >> 4) + i * 16;
    int col = (t & 15) * 4;
    float4 v = *(const float4*)&w[(size_t)(r0 + row) * 1024 + c0 + col];
    tile[row][col] = v.x; tile[row][col + 1] = v.y;
    tile[row][col + 2] = v.z; tile[row][col + 3] = v.w;
  }
  __syncthreads();
#pragma unroll
  for (int i = 0; i < 2; i++) {
    int nr = (t >> 3) + i * 32;
    int kc = (t & 7) * 8;
    u16x8 o;
#pragma unroll
    for (int j = 0; j < 8; j++) o[j] = f32_to_bf16(tile[kc + j][nr]);
    *(u16x8*)&out[(size_t)(c0 + nr) * 1024 + r0 + kc] = o;
  }
}

// per-tile fragment set: 12 x bf16x8 = 48 VGPR
struct Frags { bf16x8 afA[4], bfr[4], afB[4]; };

__device__ __forceinline__ void read_frags(Frags& f, const unsigned short* ab,
                                           const unsigned short* bb, int aRow0,
                                           int bRow0, int li, int koff) {
#pragma unroll
  for (int m = 0; m < 4; m++) f.afA[m] = ld_bf16x8(ab + (aRow0 + m * 16 + li) * 32 + koff);
#pragma unroll
  for (int n = 0; n < 4; n++) f.bfr[n] = ld_bf16x8(bb + (bRow0 + n * 16 + li) * 32 + koff);
#pragma unroll
  for (int m = 0; m < 4; m++)
    f.afB[m] = ld_bf16x8(ab + (aRow0 + 64 + m * 16 + li) * 32 + koff);
}

// ============ 256x256-tile deep-pipelined GEMM: C = A[M][K] @ Bt[N][K]^T ============
// 512 threads = 8 waves (2 wm x 4 wn); wave tile 128x64; BK=32, 4 K-tile LDS buffers.
// Cross-tile register rotation: tile tt+1's 12 fragment ds_reads are issued right
// after tile tt's mid-tile barrier and complete under tile tt's MFMA-B, so LDS reads
// always overlap MFMA. One barrier per tile; counted vmcnt(8) keeps 2 K-tiles of
// global_load_lds in flight; stage depth 4 (buf(tt) is dead during tile tt).
// LDS bank-conflict fix: physical 16B-chunk pc = lc ^ ((row>>1)&3), pre-swizzled
// GLOBAL source (global_load_lds dest stays linear) + swizzled read offset.
template <int EPI>
__global__ __launch_bounds__(512, 2) void gemm256(
    const unsigned short* __restrict__ A, const unsigned short* __restrict__ Bt,
    const float* __restrict__ b0, const float* __restrict__ b1, const float* __restrict__ b2,
    unsigned short* __restrict__ Qb, unsigned short* __restrict__ Kb, unsigned short* __restrict__ Vb,
    float* __restrict__ Out, int Ncols, int K) {
  __shared__ __align__(16) unsigned short As[4][256][32];
  __shared__ __align__(16) unsigned short Bs[4][256][32];
  const int NT = K >> 5;   // must be even (2-tile unrolled loop)
  const int nb = Ncols >> 8;
  // XCD-aware swizzle (nwg % 8 == 0 for all our launches)
  const int nwg = gridDim.x;
  const int cpx = nwg >> 3;
  const int bid = blockIdx.x;
  const int wg = (bid & 7) * cpx + (bid >> 3);
  const int tm = wg / nb, tn = wg % nb;
  const int rowBase = tm << 8, colBase = tn << 8;
  const int t = threadIdx.x;
  const int lane = t & 63;
  const int w = t >> 6;
  const int li = lane & 15, lg = lane >> 4;
  const int wm = w >> 2, wn = w & 3;
  const int aRow0 = wm * 128;   // wave's A rows within tile
  const int bRow0 = wn * 64;    // wave's Bt rows (= C cols) within tile
  // swizzled k-offset for fragment reads: (row>>1)&3 == (li>>1)&3 for all our rows
  const int koff = ((lg ^ ((li >> 1) & 3)) << 3);

  // staging: 1024 chunks of 16B per matrix per K-tile; 2 chunks/thread.
  // thread's chunk c lands at physical (row=c>>2, pc=c&3); source = logical
  // chunk lc = pc ^ ((row>>1)&3) of that row.
  const int c0 = t, c1 = t + 512;
  const int r0s = c0 >> 2, r1s = c1 >> 2;
  const int l0s = (c0 & 3) ^ ((r0s >> 1) & 3);
  const int l1s = (c1 & 3) ^ ((r1s >> 1) & 3);
  const unsigned short* gA0 = A + (size_t)(rowBase + r0s) * K + l0s * 8;
  const unsigned short* gA1 = A + (size_t)(rowBase + r1s) * K + l1s * 8;
  const unsigned short* gB0 = Bt + (size_t)(colBase + r0s) * K + l0s * 8;
  const unsigned short* gB1 = Bt + (size_t)(colBase + r1s) * K + l1s * 8;

#define STAGE_AB(tile_) do { int b_ = (tile_) & 3; int kt_ = (tile_) << 5;                    \
    __builtin_amdgcn_global_load_lds((gas_cvptr)(gA0 + kt_),                                  \
        (las_vptr)(&As[b_][0][0] + c0 * 8), 16, 0, 0);                                        \
    __builtin_amdgcn_global_load_lds((gas_cvptr)(gA1 + kt_),                                  \
        (las_vptr)(&As[b_][0][0] + c1 * 8), 16, 0, 0);                                        \
    __builtin_amdgcn_global_load_lds((gas_cvptr)(gB0 + kt_),                                  \
        (las_vptr)(&Bs[b_][0][0] + c0 * 8), 16, 0, 0);                                        \
    __builtin_amdgcn_global_load_lds((gas_cvptr)(gB1 + kt_),                                  \
        (las_vptr)(&Bs[b_][0][0] + c1 * 8), 16, 0, 0); } while (0)

  // prologue: stage tiles 0..3 (depth 4), land tile 0, read its frags
  STAGE_AB(0); STAGE_AB(1); STAGE_AB(2); STAGE_AB(3);
  WAITV12;
  BAR();

  f32x4 acc[8][4] = {};
  Frags F0, F1;
  read_frags(F0, &As[0][0][0], &Bs[0][0][0], aRow0, bRow0, li, koff);

  // body: CUR frags already in regs; prefetch NXT frags under MFMA-B.
#define TILE_BODY(tt_, CUR, NXT) do {                                                         \
    WAITL0; SB();                                                                             \
    __builtin_amdgcn_s_setprio(1);                                                            \
    _Pragma("unroll")                                                                         \
    for (int m = 0; m < 4; m++)                                                               \
      _Pragma("unroll")                                                                       \
      for (int n = 0; n < 4; n++)                                                             \
        acc[m][n] = __builtin_amdgcn_mfma_f32_16x16x32_bf16(CUR.afA[m], CUR.bfr[n],           \
                                                            acc[m][n], 0, 0, 0);              \
    __builtin_amdgcn_s_setprio(0);                                                            \
    if ((tt_) <= NT - 4)      WAITV8;                                                         \
    else if ((tt_) == NT - 3) WAITV4;                                                         \
    else if ((tt_) == NT - 2) WAITV0;                                                         \
    BAR();                                                                                    \
    if ((tt_) + 1 < NT)                                                                       \
      read_frags(NXT, &As[((tt_) + 1) & 3][0][0], &Bs[((tt_) + 1) & 3][0][0],                 \
                 aRow0, bRow0, li, koff);                                                     \
    if ((tt_) + 4 < NT) STAGE_AB((tt_) + 4);                                                  \
    __builtin_amdgcn_s_setprio(1);                                                            \
    _Pragma("unroll")                                                                         \
    for (int m = 0; m < 4; m++)                                                               \
      _Pragma("unroll")                                                                       \
      for (int n = 0; n < 4; n++)                                                             \
        acc[4 + m][n] = __builtin_amdgcn_mfma_f32_16x16x32_bf16(CUR.afB[m], CUR.bfr[n],       \
                                                                acc[4 + m][n], 0, 0, 0);      \
    __builtin_amdgcn_s_setprio(0);                                                            \
  } while (0)

  for (int tt = 0; tt < NT; tt += 2) {
    TILE_BODY(tt, F0, F1);
    TILE_BODY(tt + 1, F1, F0);
  }
#undef TILE_BODY
#undef STAGE_AB

  if (EPI == 0) {
    const int part = colBase >> 10;  // 0=Q 1=K 2=V (256 | 1024 so uniform per block)
    const float* __restrict__ bias = (part == 0) ? b0 : (part == 1) ? b1 : b2;
    unsigned short* __restrict__ dst = (part == 0) ? Qb : (part == 1) ? Kb : Vb;
#pragma unroll
    for (int mi = 0; mi < 8; mi++) {
      const int rowb = rowBase + aRow0 + mi * 16 + lg * 4;
#pragma unroll
      for (int r = 0; r < 4; r++) {
        const int row = rowb + r;
        const int b = row >> 6, s = row & 63;
#pragma unroll
        for (int n = 0; n < 4; n++) {
          const int col = colBase + bRow0 + n * 16 + li;
          const int within = col & 1023;
          const int h = within >> 6, dh = within & 63;
          float v = acc[mi][n][r] + bias[within];
          dst[(size_t)((b * 16 + h) * 64 + s) * 64 + dh] = f32_to_bf16(v);
        }
      }
    }
  } else {
#pragma unroll
    for (int mi = 0; mi < 8; mi++) {
      const int rowb = rowBase + aRow0 + mi * 16 + lg * 4;
#pragma unroll
      for (int r = 0; r < 4; r++) {
#pragma unroll
        for (int n = 0; n < 4; n++) {
          const int col = colBase + bRow0 + n * 16 + li;
          float v = acc[mi][n][r] + b0[col];
          v = 0.5f * v * (1.0f + erff(v * 0.70710678118654752f));
          Out[(size_t)(rowb + r) * 1024 + col] = v;
        }
      }
    }
  }
}

// ---------------- attention per (b,h): 64x64, softmax, PV ----------------
__global__ __launch_bounds__(256) void attn(
    const unsigned short* __restrict__ Qb, const unsigned short* __restrict__ Kb,
    const unsigned short* __restrict__ Vb, unsigned short* __restrict__ ctx) {
  __shared__ __align__(16) unsigned short Qs[64][72];
  __shared__ __align__(16) unsigned short Ks[64][72];
  __shared__ __align__(16) unsigned short Vt[64][72];   // transposed: [dh][s]
  __shared__ __align__(16) unsigned short Ps[64][72];
  const int bh = blockIdx.x;
  const int b = bh >> 4, h = bh & 15;
  const int t = threadIdx.x, lane = t & 63, w = t >> 6;
  const int li = lane & 15, lg = lane >> 4;
  const unsigned short* __restrict__ Qg = Qb + (size_t)bh * 4096;
  const unsigned short* __restrict__ Kg = Kb + (size_t)bh * 4096;
  const unsigned short* __restrict__ Vg = Vb + (size_t)bh * 4096;

#pragma unroll
  for (int i = 0; i < 2; i++) {
    const int c = t + i * 256;
    const int row = c >> 3, col8 = (c & 7) * 8;
    *(u16x8*)&Qs[row][col8] = *(const u16x8*)&Qg[row * 64 + col8];
    *(u16x8*)&Ks[row][col8] = *(const u16x8*)&Kg[row * 64 + col8];
    u16x8 v = *(const u16x8*)&Vg[row * 64 + col8];
#pragma unroll
    for (int j = 0; j < 8; j++) Vt[col8 + j][row] = v[j];
  }
  __syncthreads();

  f32x4 sc[4] = {};
#pragma unroll
  for (int ks = 0; ks < 2; ks++) {
    bf16x8 qa = ld_bf16x8(&Qs[w * 16 + li][ks * 32 + lg * 8]);
#pragma unroll
    for (int n = 0; n < 4; n++) {
      bf16x8 kf = ld_bf16x8(&Ks[n * 16 + li][ks * 32 + lg * 8]);
      sc[n] = __builtin_amdgcn_mfma_f32_16x16x32_bf16(qa, kf, sc[n], 0, 0, 0);
    }
  }

#pragma unroll
  for (int r = 0; r < 4; r++) {
    float v0 = sc[0][r] * 0.03125f, v1 = sc[1][r] * 0.03125f;
    float v2 = sc[2][r] * 0.03125f, v3 = sc[3][r] * 0.03125f;
    float mx = fmaxf(fmaxf(v0, v1), fmaxf(v2, v3));
#pragma unroll
    for (int off = 1; off < 16; off <<= 1) mx = fmaxf(mx, __shfl_xor(mx, off, 64));
    float e0 = __expf(v0 - mx), e1 = __expf(v1 - mx);
    float e2 = __expf(v2 - mx), e3 = __expf(v3 - mx);
    float sum = e0 + e1 + e2 + e3;
#pragma unroll
    for (int off = 1; off < 16; off <<= 1) sum += __shfl_xor(sum, off, 64);
    float is = 1.0f / sum;
    const int q = w * 16 + lg * 4 + r;
    Ps[q][0 * 16 + li] = f32_to_bf16(e0 * is);
    Ps[q][1 * 16 + li] = f32_to_bf16(e1 * is);
    Ps[q][2 * 16 + li] = f32_to_bf16(e2 * is);
    Ps[q][3 * 16 + li] = f32_to_bf16(e3 * is);
  }
  __syncthreads();

  f32x4 oc[4] = {};
#pragma unroll
  for (int ks = 0; ks < 2; ks++) {
    bf16x8 pa = ld_bf16x8(&Ps[w * 16 + li][ks * 32 + lg * 8]);
#pragma unroll
    for (int n = 0; n < 4; n++) {
      bf16x8 vf = ld_bf16x8(&Vt[n * 16 + li][ks * 32 + lg * 8]);
      oc[n] = __builtin_amdgcn_mfma_f32_16x16x32_bf16(pa, vf, oc[n], 0, 0, 0);
    }
  }
#pragma unroll
  for (int n = 0; n < 4; n++)
#pragma unroll
    for (int r = 0; r < 4; r++)
      ctx[(size_t)(b * 64 + w * 16 + lg * 4 + r) * 1024 + h * 64 + n * 16 + li] =
          f32_to_bf16(oc[n][r]);
}

extern "C" void kernel_launch(void* const* d_in, const int* in_sizes, int n_in,
                              void* d_out, int out_size, void* d_ws, size_t ws_size,
                              hipStream_t stream) {
  const float* x  = (const float*)d_in[0];
  const float* wq = (const float*)d_in[1];
  const float* bq = (const float*)d_in[2];
  const float* wk = (const float*)d_in[3];
  const float* bk = (const float*)d_in[4];
  const float* wv = (const float*)d_in[5];
  const float* bv = (const float*)d_in[6];
  const float* wo = (const float*)d_in[7];
  const float* bo = (const float*)d_in[8];
  float* out = (float*)d_out;

  const int D = 1024;
  const int M = in_sizes[0] / D;  // B*S = 32768

  char* ws = (char*)d_ws;
  unsigned short* xb    = (unsigned short*)ws;
  unsigned short* wqkvT = (unsigned short*)(ws + (size_t)M * 1024 * 2);
  unsigned short* woT   = wqkvT + (size_t)3 * 1024 * 1024;
  unsigned short* Qb    = woT + (size_t)1024 * 1024;
  unsigned short* Kb    = Qb + (size_t)M * 1024;
  unsigned short* Vb    = Kb + (size_t)M * 1024;
  unsigned short* ctx   = xb;  // reuse: x no longer needed after QKV GEMM

  cvt_x<<<2048, 256, 0, stream>>>(x, xb, M * D / 4);
  cvt_w<<<dim3(16, 16, 4), 256, 0, stream>>>(wq, wk, wv, wo, wqkvT, woT);
  gemm256<0><<<(M / 256) * (3072 / 256), 512, 0, stream>>>(
      xb, wqkvT, bq, bk, bv, Qb, Kb, Vb, nullptr, 3072, 1024);
  attn<<<(M / 64) * 16, 256, 0, stream>>>(Qb, Kb, Vb, ctx);
  gemm256<1><<<(M / 256) * (1024 / 256), 512, 0, stream>>>(
      ctx, woT, bo, nullptr, nullptr, nullptr, nullptr, nullptr, out, 1024, 1024);
}